// Round 9
// baseline (174.439 us; speedup 1.0000x reference)
//
#include <hip/hip_runtime.h>

// KNN k-th smallest distance — single MFMA pass + candidate-subset rescan.
// dist = sqrt(2 - 2*dot(zn,rn)); sorted(dist)[k] == (k+1)-th LARGEST dot.
//  1) normalize_bf16: fused z+ref rows -> L2-normalized bf16
//  2) knn_maxes:     MFMA dots (8-wave/256q attention shape), per-(row,
//                    chunk,hi,residue) subset MAX in-register -> maxes
//  3) knn_threshold: per row, T = (k+1)-th largest of 2048 subset maxes;
//                    emit candidate subset list {s : max_s >= T} (~11)
//  4) knn_rescan:    per row, recompute dots ONLY in candidate subsets
//                    (~11 x 24 = 264 dots) and output the (k+1)-th largest.
//
// Round-9 rationale: six structurally different MFMA passes all measure
// 43-46us (= m233's 2-phase plateau, ~590 TF); the schedule is a wall.  So
// cut the ALGORITHM: pass 2 recomputed 26 GFLOP to find ~15-40 survivors.
// Every top-(k+1) dot lives in a subset whose max >= T, and T is the
// (k+1)-th largest subset max -> only ~11 candidate subsets/row.  Rescan is
// 0.28 GFLOP + ~138MB L2/L3 gather, replacing a 44us MFMA pass.
//
// Exactness: candidate selection uses the SAME MFMA-produced maxes as T, so
// coverage is exact (top-11 MFMA dots all live in candidate subsets; taking
// the 11th largest of all candidate-subset dots == 11th largest overall).
// Rescan recomputes dots as f32 sums of the identical exact bf16 products
// (bf16xbf16 is exact in f32) -> ordering noise <= ~2e-5 in dot space,
// ~1e-4 in dist, far below the 2.39e-2 tolerance (bf16 rounding already
// contributes 3.5e-4/dot; k-th order statistic is 1-Lipschitz).
// Subsets (chunk by, hi, residue r) PARTITION each row's refs: ref class
// c = ref&31 -> r = (c&3)|((c>>3)<<2), hi = (c>>2)&1; offsets {0,32} and
// tails are masked identically in knn_maxes (ok0/ok1) and knn_rescan
// (ref < c1).  Tie overflow (>32 candidates) falls back to a full exact
// scan of the row inside knn_rescan.

#define D_DIM 128
#define TQB 256        // queries per block (8 waves x 32 rows)
#define BR 64          // refs per block iteration
#define NCH 64         // ref chunks; grid 8*64=512 blocks; 512%8==0
#define NSUB (NCH * 32) // subsets per row = 2048  (chunk x hi x residue)
#define KK 11          // selection slots (k=10 -> 11th largest)
#define NCAND 32       // candidate-subset capacity per row (>=11; ties only)
#define SLOTS 26       // max refs per subset slot-grid: 13 tiles x {0,32}
#define DN 2816        // rescan LDS dot buffer (256 threads * KK fallback)

typedef __bf16 bf16_t;
typedef bf16_t bf16x8 __attribute__((ext_vector_type(8)));
typedef float f32x16 __attribute__((ext_vector_type(16)));

__device__ __forceinline__ unsigned short f2bf(float f) {
    unsigned u = __float_as_uint(f);
    return (unsigned short)((u + 0x7fffu + ((u >> 16) & 1u)) >> 16);  // RNE
}

__global__ __launch_bounds__(256) void normalize_bf16(
    const float* __restrict__ z, const float* __restrict__ ref,
    unsigned short* __restrict__ zb, unsigned short* __restrict__ rb,
    int N, int M)
{
    const int w = threadIdx.x >> 6;
    const int l = threadIdx.x & 63;
    const int row = blockIdx.x * 4 + w;
    if (row >= N + M) return;
    const float* in; unsigned short* out; int r;
    if (row < N) { in = z;   out = zb; r = row; }
    else         { in = ref; out = rb; r = row - N; }
    const float2 v = ((const float2*)in)[(size_t)r * 64 + l];
    float ss = v.x * v.x + v.y * v.y;
    #pragma unroll
    for (int off = 32; off > 0; off >>= 1) ss += __shfl_xor(ss, off);
    const float inv = rsqrtf(ss);
    ushort2 o; o.x = f2bf(v.x * inv); o.y = f2bf(v.y * inv);
    ((ushort2*)out)[(size_t)r * 64 + l] = o;
}

// async global->LDS, 16B per lane; LDS dest is wave-uniform base + lane*16.
__device__ __forceinline__ void gld_lds16(const unsigned short* g,
                                          unsigned short* l) {
    __builtin_amdgcn_global_load_lds(
        (__attribute__((address_space(1))) void*)g,
        (__attribute__((address_space(3))) void*)l, 16, 0, 0);
}

// Single MFMA pass: subset maxes only (r8 body, hi-split subset write).
__global__ __launch_bounds__(512) void knn_maxes(
    const unsigned short* __restrict__ zb, const unsigned short* __restrict__ rb,
    float* __restrict__ maxes, int N, int M, int chunk)
{
    __shared__ __align__(16) unsigned short Bt[2 * BR * D_DIM];

    // T1 XCD swizzle: XCD k owns ref-chunks [8k,8k+8) exclusively (1.6MB,
    // L2-fit); all 8 q-blocks of a chunk land on the same XCD.
    const int nwg = 8 * NCH;                              // 512, %8 == 0
    const int bid = (int)blockIdx.x + 8 * (int)blockIdx.y;
    const int swz = (bid & 7) * (nwg >> 3) + (bid >> 3);
    const int bx = swz & 7;
    const int by = swz >> 3;

    const int t = threadIdx.x;
    const int lane = t & 63;
    const int w = t >> 6;
    const int quad = lane >> 4;
    const int ln = lane & 15;
    const int l31 = lane & 31;
    const int hi = lane >> 5;
    const int row = bx * TQB + w * 32 + l31;   // this lane's q-row
    const int c0 = by * chunk;
    const int c1 = min(c0 + chunk, M);
    const int clen = c1 - c0;
    const int nt = (clen + BR - 1) / BR;

    // Q fragments (B operand), loop-invariant, from L2-resident zb.
    bf16x8 qfr[8];
    #pragma unroll
    for (int ks = 0; ks < 8; ++ks)
        qfr[ks] = *(const bf16x8*)&zb[(size_t)row * D_DIM + ks * 16 + hi * 8];

    float mx[16];
    #pragma unroll
    for (int r = 0; r < 16; ++r) mx[r] = -3.0f;

    auto stage = [&](int half, int tile) {
        const int s0 = c0 + tile * BR;
        #pragma unroll
        for (int i = 0; i < 2; ++i) {
            const int r = w * 8 + i * 4 + quad;
            int g = s0 + r; if (g > M - 1) g = M - 1;
            const int sl = ln ^ (r & 15);               // inverse-swizzled slot
            gld_lds16(&rb[(size_t)g * D_DIM + sl * 8],
                      &Bt[half * (BR * D_DIM) + (w * 8 + i * 4) * D_DIM]);
        }
    };

    stage(0, 0);
    stage(1, nt > 1 ? 1 : 0);

    for (int it = 0; it < nt; ++it) {
        if (it + 1 < nt) asm volatile("s_waitcnt vmcnt(2)" ::: "memory");
        else             asm volatile("s_waitcnt vmcnt(0)" ::: "memory");
        __builtin_amdgcn_s_barrier();
        asm volatile("" ::: "memory");
        __builtin_amdgcn_sched_barrier(0);

        const int cur = it & 1;
        const unsigned short* Bc = &Bt[cur * (BR * D_DIM)];

        f32x16 acc0 = {0,0,0,0,0,0,0,0,0,0,0,0,0,0,0,0};
        f32x16 acc1 = {0,0,0,0,0,0,0,0,0,0,0,0,0,0,0,0};

        __builtin_amdgcn_s_setprio(1);
        #pragma unroll
        for (int ks = 0; ks < 8; ++ks) {
            const int sl = ((ks * 2 + hi) ^ ln) * 8;    // swizzled 16B slot
            bf16x8 a0 = *(const bf16x8*)&Bc[(l31)      * D_DIM + sl];
            bf16x8 a1 = *(const bf16x8*)&Bc[(32 + l31) * D_DIM + sl];
            acc0 = __builtin_amdgcn_mfma_f32_32x32x16_bf16(a0, qfr[ks], acc0, 0, 0, 0);
            acc1 = __builtin_amdgcn_mfma_f32_32x32x16_bf16(a1, qfr[ks], acc1, 0, 0, 0);
        }
        __builtin_amdgcn_s_setprio(0);

        // acc0/acc1 reg r = dot(q=row, ref = c0+it*64+{0,32}+crow),
        // crow = (r&3)+8*(r>>2)+4*hi  [m74/m101 verified layout].
        const int rem = clen - it * BR;
        if (rem >= BR) {
            #pragma unroll
            for (int r = 0; r < 16; ++r)
                mx[r] = fmaxf(mx[r], fmaxf(acc0[r], acc1[r]));
        } else {
            #pragma unroll
            for (int r = 0; r < 16; ++r) {
                const int crow = (r & 3) + 8 * (r >> 2) + 4 * hi;
                if (crow < rem)      mx[r] = fmaxf(mx[r], acc0[r]);
                if (32 + crow < rem) mx[r] = fmaxf(mx[r], acc1[r]);
            }
        }

        __builtin_amdgcn_sched_barrier(0);
        asm volatile("" ::: "memory");
        __builtin_amdgcn_s_barrier();
        if (it + 2 < nt) stage(cur, it + 2);
    }

    // hi-split subset write: 16 contiguous floats per lane (4 x float4).
    float* mp = &maxes[(size_t)row * NSUB + by * 32 + hi * 16];
    #pragma unroll
    for (int r4 = 0; r4 < 4; ++r4) {
        float4 v4 = { mx[r4 * 4], mx[r4 * 4 + 1], mx[r4 * 4 + 2], mx[r4 * 4 + 3] };
        *(float4*)&mp[r4 * 4] = v4;
    }
}

// Per-lane sorted top-(KK) slots, then kk+1 global max-extractions with
// static-shift pop (rule #20: no dynamic register indexing).
__device__ __forceinline__ float kth_largest_64(float* s, int kk, int t) {
    float cur = -3.0f;
    for (int it = 0; it <= kk; ++it) {
        float m = s[0];
        #pragma unroll
        for (int off = 32; off > 0; off >>= 1) m = fmaxf(m, __shfl_xor(m, off));
        cur = m;
        unsigned long long b = __ballot(s[0] == m);
        bool owner = ((int)(__ffsll(b) - 1) == t);
        #pragma unroll
        for (int j = 0; j < KK - 1; ++j) s[j] = owner ? s[j + 1] : s[j];
        if (owner) s[KK - 1] = -3.0f;
    }
    return cur;
}

__global__ __launch_bounds__(64) void knn_threshold(
    const float* __restrict__ maxes, const int* __restrict__ kp,
    int* __restrict__ cand, int* __restrict__ ccnt)
{
    const int row = blockIdx.x;
    const int t = threadIdx.x;
    float s[KK];
    #pragma unroll
    for (int j = 0; j < KK; ++j) s[j] = -3.0f;
    #pragma unroll
    for (int i = 0; i < NSUB / 64; ++i) {     // 32 coalesced loads
        float v = maxes[(size_t)row * NSUB + t + 64 * i];
        #pragma unroll
        for (int j = 0; j < KK; ++j) {        // descending sorted insert
            float hi = fmaxf(s[j], v), lo = fminf(s[j], v);
            s[j] = hi; v = lo;
        }
    }
    const int kk = *kp;   // 10
    const float T = kth_largest_64(s, kk, t);

    __shared__ int cn;
    if (t == 0) cn = 0;
    __syncthreads();
    #pragma unroll
    for (int i = 0; i < NSUB / 64; ++i) {     // reload; append candidates
        float v = maxes[(size_t)row * NSUB + t + 64 * i];
        if (v >= T) {
            int slot = atomicAdd(&cn, 1);
            if (slot < NCAND) cand[(size_t)row * NCAND + slot] = t + 64 * i;
        }
    }
    __syncthreads();
    if (t == 0) ccnt[row] = cn;
}

// Per row: recompute dots only in candidate subsets; output (k+1)-th largest.
__global__ __launch_bounds__(256) void knn_rescan(
    const unsigned short* __restrict__ zb, const unsigned short* __restrict__ rb,
    const int* __restrict__ cand, const int* __restrict__ ccnt,
    const int* __restrict__ kp, float* __restrict__ out,
    int M, int chunk)
{
    const int row = blockIdx.x;
    const int t = threadIdx.x;
    __shared__ float qs[D_DIM];
    __shared__ float dbuf[DN];

    if (t < D_DIM)
        qs[t] = (float)(((const bf16_t*)zb)[(size_t)row * D_DIM + t]);
    for (int i = t; i < DN; i += 256) dbuf[i] = -3.0f;
    __syncthreads();

    const int cn = ccnt[row];
    const int kk = *kp;

    auto dot_of = [&](int ref) -> float {
        const unsigned short* rp = &rb[(size_t)ref * D_DIM];
        float acc = 0.f;
        #pragma unroll
        for (int j = 0; j < D_DIM; j += 8) {
            bf16x8 rv = *(const bf16x8*)(rp + j);
            const float4 q0 = *(const float4*)&qs[j];
            const float4 q1 = *(const float4*)&qs[j + 4];
            acc = fmaf((float)rv[0], q0.x, acc);
            acc = fmaf((float)rv[1], q0.y, acc);
            acc = fmaf((float)rv[2], q0.z, acc);
            acc = fmaf((float)rv[3], q0.w, acc);
            acc = fmaf((float)rv[4], q1.x, acc);
            acc = fmaf((float)rv[5], q1.y, acc);
            acc = fmaf((float)rv[6], q1.z, acc);
            acc = fmaf((float)rv[7], q1.w, acc);
        }
        return acc;
    };

    if (cn <= NCAND) {
        // Normal path: enumerate candidate subsets' refs (<= 32*26 = 832).
        const int work = cn * SLOTS;
        for (int gs = t; gs < work; gs += 256) {
            const int ci = gs / SLOTS;
            const int sl = gs - ci * SLOTS;
            const int s  = cand[(size_t)row * NCAND + ci];
            const int by = s >> 5;
            const int r  = s & 15;
            const int h2 = (s >> 4) & 1;
            const int base = (r & 3) + 8 * (r >> 2) + 4 * h2;
            const int c0 = by * chunk;
            const int c1 = min(c0 + chunk, M);
            const int ref = c0 + (sl >> 1) * 64 + (sl & 1) * 32 + base;
            if (ref < c1) dbuf[gs] = dot_of(ref);
        }
    } else {
        // Tie-overflow fallback (~never): exact full scan of this row.
        float s[KK];
        #pragma unroll
        for (int j = 0; j < KK; ++j) s[j] = -3.0f;
        for (int g = t; g < M; g += 256) {
            float v = dot_of(g);
            #pragma unroll
            for (int j = 0; j < KK; ++j) {
                float hi = fmaxf(s[j], v), lo = fminf(s[j], v);
                s[j] = hi; v = lo;
            }
        }
        #pragma unroll
        for (int j = 0; j < KK; ++j) dbuf[t * KK + j] = s[j];   // 256*11 = DN
    }
    __syncthreads();

    if (t < 64) {   // wave 0: (kk+1)-th largest over dbuf
        float s[KK];
        #pragma unroll
        for (int j = 0; j < KK; ++j) s[j] = -3.0f;
        #pragma unroll
        for (int j = 0; j < DN / 64; ++j) {   // 44 values per lane
            float v = dbuf[t + 64 * j];
            #pragma unroll
            for (int q = 0; q < KK; ++q) {
                float hi = fmaxf(s[q], v), lo = fminf(s[q], v);
                s[q] = hi; v = lo;
            }
        }
        const float cur = kth_largest_64(s, kk, t);
        if (t == 0) out[row] = sqrtf(fmaxf(2.0f - 2.0f * cur, 1e-12f));
    }
}

extern "C" void kernel_launch(void* const* d_in, const int* in_sizes, int n_in,
                              void* d_out, int out_size, void* d_ws, size_t ws_size,
                              hipStream_t stream) {
    const float* z   = (const float*)d_in[0];
    const float* ref = (const float*)d_in[1];
    const int*   kp  = (const int*)d_in[2];
    float* out = (float*)d_out;

    const int N = in_sizes[0] / D_DIM;   // 2048
    const int M = in_sizes[1] / D_DIM;   // 50000

    unsigned short* zbuf = (unsigned short*)d_ws;             // N*128 bf16
    unsigned short* rbuf = zbuf + (size_t)N * D_DIM;          // M*128 bf16
    float* maxes = (float*)(rbuf + (size_t)M * D_DIM);        // N*NSUB f32 (16MB)
    int*   cand  = (int*)(maxes + (size_t)N * NSUB);          // N*NCAND i32
    int*   ccnt  = cand + (size_t)N * NCAND;                  // N i32

    normalize_bf16<<<(N + M + 3) / 4, 256, 0, stream>>>(z, ref, zbuf, rbuf, N, M);

    const int chunk = (M + NCH - 1) / NCH;    // 782
    dim3 grid(N / TQB, NCH);                  // 8 x 64 = 512 blocks

    knn_maxes<<<grid, 512, 0, stream>>>(zbuf, rbuf, maxes, N, M, chunk);
    knn_threshold<<<N, 64, 0, stream>>>(maxes, kp, cand, ccnt);
    knn_rescan<<<N, 256, 0, stream>>>(zbuf, rbuf, cand, ccnt, kp, out, M, chunk);
}

// Round 10
// 137.354 us; speedup vs baseline: 1.2700x; 1.2700x over previous
//
#include <hip/hip_runtime.h>

// KNN k-th smallest distance — single MFMA pass + fused candidate select.
// dist = sqrt(2 - 2*dot(zn,rn)); sorted(dist)[k] == (k+1)-th LARGEST dot.
//  1) normalize_bf16: fused z+ref rows -> L2-normalized bf16
//  2) knn_maxes:     MFMA dots (8-wave/256q attention shape), per-(row,
//                    chunk,hi,residue) subset MAX in-register -> maxes
//  3) knn_select:    per row (fused): T = (k+1)-th largest subset max ->
//                    candidate subsets (LDS) -> cooperative 8-lane coalesced
//                    dot recompute of ONLY candidate refs (~11 x 24) ->
//                    (k+1)-th largest -> dist.
//
// Round-10 fixes to r9's rescan (55us, latency-bound: 0 MFMA, VALU 15%,
// 64-way 16B scatter per instruction, wave0 scanning 2816 mostly-dead LDS
// slots, cand round-trip through global):
//  - fuse threshold+rescan: candidates live in LDS, one launch less
//  - 8-lane cooperative dots: group reads ref row as 2 contiguous 128B
//    segments (coalesced), butterfly shfl reduce
//  - selection scans only W = cn*slots (~290) live entries, not 2816
//  - q slice preloaded into 16 regs/lane during wave0's threshold phase
//
// Exactness: candidate selection uses the SAME MFMA-produced maxes as T, so
// coverage is exact (every top-11 dot lives in a subset whose max >= T; the
// 11th largest of all candidate-subset dots == 11th largest overall).
// Recomputed dots sum the identical exact bf16 products in f32 (different
// order) -> ordering noise ~2e-5 in dot space, ~1e-4 in dist, far below the
// 2.39e-2 tolerance.  Subsets (chunk by, hi, residue r) PARTITION each
// row's refs; tails masked identically (ref < c1) in both kernels.  Tie
// overflow (cn > NCAND) falls back to an exact full scan of the row.

#define D_DIM 128
#define TQB 256        // queries per block (8 waves x 32 rows)
#define BR 64          // refs per block iteration
#define NCH 64         // ref chunks; grid 8*64=512 blocks; 512%8==0
#define NSUB (NCH * 32) // subsets per row = 2048  (chunk x hi x residue)
#define KK 11          // selection slots (k=10 -> 11th largest)
#define NCAND 32       // candidate-subset capacity per row (>=11; ties only)
#define SLOTS 26       // max slots per subset: 13 tiles x {0,32}
#define DNF 2816       // LDS dot buffer: max(NCAND*SLOTS=832, 256*KK=2816)

typedef __bf16 bf16_t;
typedef bf16_t bf16x8 __attribute__((ext_vector_type(8)));
typedef float f32x16 __attribute__((ext_vector_type(16)));

__device__ __forceinline__ unsigned short f2bf(float f) {
    unsigned u = __float_as_uint(f);
    return (unsigned short)((u + 0x7fffu + ((u >> 16) & 1u)) >> 16);  // RNE
}

__global__ __launch_bounds__(256) void normalize_bf16(
    const float* __restrict__ z, const float* __restrict__ ref,
    unsigned short* __restrict__ zb, unsigned short* __restrict__ rb,
    int N, int M)
{
    const int w = threadIdx.x >> 6;
    const int l = threadIdx.x & 63;
    const int row = blockIdx.x * 4 + w;
    if (row >= N + M) return;
    const float* in; unsigned short* out; int r;
    if (row < N) { in = z;   out = zb; r = row; }
    else         { in = ref; out = rb; r = row - N; }
    const float2 v = ((const float2*)in)[(size_t)r * 64 + l];
    float ss = v.x * v.x + v.y * v.y;
    #pragma unroll
    for (int off = 32; off > 0; off >>= 1) ss += __shfl_xor(ss, off);
    const float inv = rsqrtf(ss);
    ushort2 o; o.x = f2bf(v.x * inv); o.y = f2bf(v.y * inv);
    ((ushort2*)out)[(size_t)r * 64 + l] = o;
}

// async global->LDS, 16B per lane; LDS dest is wave-uniform base + lane*16.
__device__ __forceinline__ void gld_lds16(const unsigned short* g,
                                          unsigned short* l) {
    __builtin_amdgcn_global_load_lds(
        (__attribute__((address_space(1))) void*)g,
        (__attribute__((address_space(3))) void*)l, 16, 0, 0);
}

// Single MFMA pass: subset maxes only (r9 body, verified passing).
__global__ __launch_bounds__(512) void knn_maxes(
    const unsigned short* __restrict__ zb, const unsigned short* __restrict__ rb,
    float* __restrict__ maxes, int N, int M, int chunk)
{
    __shared__ __align__(16) unsigned short Bt[2 * BR * D_DIM];

    // T1 XCD swizzle: XCD k owns ref-chunks [8k,8k+8) exclusively (1.6MB,
    // L2-fit); all 8 q-blocks of a chunk land on the same XCD.
    const int nwg = 8 * NCH;                              // 512, %8 == 0
    const int bid = (int)blockIdx.x + 8 * (int)blockIdx.y;
    const int swz = (bid & 7) * (nwg >> 3) + (bid >> 3);
    const int bx = swz & 7;
    const int by = swz >> 3;

    const int t = threadIdx.x;
    const int lane = t & 63;
    const int w = t >> 6;
    const int quad = lane >> 4;
    const int ln = lane & 15;
    const int l31 = lane & 31;
    const int hi = lane >> 5;
    const int row = bx * TQB + w * 32 + l31;   // this lane's q-row
    const int c0 = by * chunk;
    const int c1 = min(c0 + chunk, M);
    const int clen = c1 - c0;
    const int nt = (clen + BR - 1) / BR;

    // Q fragments (B operand), loop-invariant, from L2-resident zb.
    bf16x8 qfr[8];
    #pragma unroll
    for (int ks = 0; ks < 8; ++ks)
        qfr[ks] = *(const bf16x8*)&zb[(size_t)row * D_DIM + ks * 16 + hi * 8];

    float mx[16];
    #pragma unroll
    for (int r = 0; r < 16; ++r) mx[r] = -3.0f;

    auto stage = [&](int half, int tile) {
        const int s0 = c0 + tile * BR;
        #pragma unroll
        for (int i = 0; i < 2; ++i) {
            const int r = w * 8 + i * 4 + quad;
            int g = s0 + r; if (g > M - 1) g = M - 1;
            const int sl = ln ^ (r & 15);               // inverse-swizzled slot
            gld_lds16(&rb[(size_t)g * D_DIM + sl * 8],
                      &Bt[half * (BR * D_DIM) + (w * 8 + i * 4) * D_DIM]);
        }
    };

    stage(0, 0);
    stage(1, nt > 1 ? 1 : 0);

    for (int it = 0; it < nt; ++it) {
        if (it + 1 < nt) asm volatile("s_waitcnt vmcnt(2)" ::: "memory");
        else             asm volatile("s_waitcnt vmcnt(0)" ::: "memory");
        __builtin_amdgcn_s_barrier();
        asm volatile("" ::: "memory");
        __builtin_amdgcn_sched_barrier(0);

        const int cur = it & 1;
        const unsigned short* Bc = &Bt[cur * (BR * D_DIM)];

        f32x16 acc0 = {0,0,0,0,0,0,0,0,0,0,0,0,0,0,0,0};
        f32x16 acc1 = {0,0,0,0,0,0,0,0,0,0,0,0,0,0,0,0};

        __builtin_amdgcn_s_setprio(1);
        #pragma unroll
        for (int ks = 0; ks < 8; ++ks) {
            const int sl = ((ks * 2 + hi) ^ ln) * 8;    // swizzled 16B slot
            bf16x8 a0 = *(const bf16x8*)&Bc[(l31)      * D_DIM + sl];
            bf16x8 a1 = *(const bf16x8*)&Bc[(32 + l31) * D_DIM + sl];
            acc0 = __builtin_amdgcn_mfma_f32_32x32x16_bf16(a0, qfr[ks], acc0, 0, 0, 0);
            acc1 = __builtin_amdgcn_mfma_f32_32x32x16_bf16(a1, qfr[ks], acc1, 0, 0, 0);
        }
        __builtin_amdgcn_s_setprio(0);

        // acc0/acc1 reg r = dot(q=row, ref = c0+it*64+{0,32}+crow),
        // crow = (r&3)+8*(r>>2)+4*hi  [m74/m101 verified layout].
        const int rem = clen - it * BR;
        if (rem >= BR) {
            #pragma unroll
            for (int r = 0; r < 16; ++r)
                mx[r] = fmaxf(mx[r], fmaxf(acc0[r], acc1[r]));
        } else {
            #pragma unroll
            for (int r = 0; r < 16; ++r) {
                const int crow = (r & 3) + 8 * (r >> 2) + 4 * hi;
                if (crow < rem)      mx[r] = fmaxf(mx[r], acc0[r]);
                if (32 + crow < rem) mx[r] = fmaxf(mx[r], acc1[r]);
            }
        }

        __builtin_amdgcn_sched_barrier(0);
        asm volatile("" ::: "memory");
        __builtin_amdgcn_s_barrier();
        if (it + 2 < nt) stage(cur, it + 2);
    }

    // hi-split subset write: subset s = by*32 + hi*16 + r.
    float* mp = &maxes[(size_t)row * NSUB + by * 32 + hi * 16];
    #pragma unroll
    for (int r4 = 0; r4 < 4; ++r4) {
        float4 v4 = { mx[r4 * 4], mx[r4 * 4 + 1], mx[r4 * 4 + 2], mx[r4 * 4 + 3] };
        *(float4*)&mp[r4 * 4] = v4;
    }
}

// Per-lane sorted top-(KK) slots, then kk+1 global max-extractions with
// static-shift pop (rule #20: no dynamic register indexing).
__device__ __forceinline__ float kth_largest_64(float* s, int kk, int t) {
    float cur = -3.0f;
    for (int it = 0; it <= kk; ++it) {
        float m = s[0];
        #pragma unroll
        for (int off = 32; off > 0; off >>= 1) m = fmaxf(m, __shfl_xor(m, off));
        cur = m;
        unsigned long long b = __ballot(s[0] == m);
        bool owner = ((int)(__ffsll(b) - 1) == t);
        #pragma unroll
        for (int j = 0; j < KK - 1; ++j) s[j] = owner ? s[j + 1] : s[j];
        if (owner) s[KK - 1] = -3.0f;
    }
    return cur;
}

// Fused per-row select: threshold + candidate gather + exact (k+1)-th.
__global__ __launch_bounds__(256) void knn_select(
    const unsigned short* __restrict__ zb, const unsigned short* __restrict__ rb,
    const float* __restrict__ maxes, const int* __restrict__ kp,
    float* __restrict__ out, int M, int chunk)
{
    const int row = blockIdx.x;
    const int t = threadIdx.x;
    __shared__ float dbuf[DNF];
    __shared__ int cand_s[NCAND];
    __shared__ int cn_s;

    const int kk = *kp;   // 10
    if (t == 0) cn_s = 0;

    // Phase A (wave 0): T = (kk+1)-th largest subset max; candidate append.
    if (t < 64) {
        float s[KK];
        #pragma unroll
        for (int j = 0; j < KK; ++j) s[j] = -3.0f;
        #pragma unroll
        for (int i = 0; i < NSUB / 64; ++i) {     // 32 coalesced loads
            float v = maxes[(size_t)row * NSUB + t + 64 * i];
            #pragma unroll
            for (int j = 0; j < KK; ++j) {        // descending sorted insert
                float hi = fmaxf(s[j], v), lo = fminf(s[j], v);
                s[j] = hi; v = lo;
            }
        }
        const float T = kth_largest_64(s, kk, t);
        #pragma unroll
        for (int i = 0; i < NSUB / 64; ++i) {     // reload (L1-hot); append
            float v = maxes[(size_t)row * NSUB + t + 64 * i];
            if (v >= T) {
                int sl = atomicAdd(&cn_s, 1);
                if (sl < NCAND) cand_s[sl] = t + 64 * i;
            }
        }
    }

    // Meanwhile (all waves): q slice into regs.  Lane gl covers elements
    // [gl*8, gl*8+8) and [64+gl*8, 64+gl*8+8) -- the 8-lane group jointly
    // covers all 128.
    const int gl = t & 7;
    const int grp = t >> 3;                       // 0..31 groups per block
    float q0r[8], q1r[8];
    {
        bf16x8 qv0 = *(const bf16x8*)&zb[(size_t)row * D_DIM + gl * 8];
        bf16x8 qv1 = *(const bf16x8*)&zb[(size_t)row * D_DIM + 64 + gl * 8];
        #pragma unroll
        for (int e = 0; e < 8; ++e) { q0r[e] = (float)qv0[e]; q1r[e] = (float)qv1[e]; }
    }
    __syncthreads();

    const int cn = cn_s;
    const int slots = ((chunk + 63) >> 6) * 2;    // tiles x {0,32}; 26 here
    int nsel;

    if (cn <= NCAND && slots <= SLOTS) {
        // Normal path: recompute candidate subsets' dots cooperatively.
        const int W = cn * slots;                 // <= 832 live slots
        for (int i = t; i < W; i += 256) dbuf[i] = -3.0f;
        __syncthreads();
        for (int ci = 0; ci < cn; ++ci) {
            const int s  = cand_s[ci];
            const int by = s >> 5;
            const int h2 = (s >> 4) & 1;
            const int r  = s & 15;
            const int base = (r & 3) + 8 * (r >> 2) + 4 * h2;
            const int c0 = by * chunk;
            const int c1 = min(c0 + chunk, M);
            for (int sl = grp; sl < slots; sl += 32) {
                const int ref = c0 + (sl >> 1) * 64 + (sl & 1) * 32 + base;
                const bool valid = ref < c1;
                float p = 0.f;
                if (valid) {
                    const unsigned short* rp = &rb[(size_t)ref * D_DIM + gl * 8];
                    bf16x8 r0 = *(const bf16x8*)rp;          // coalesced 128B
                    bf16x8 r1 = *(const bf16x8*)(rp + 64);   // per 8-lane group
                    #pragma unroll
                    for (int e = 0; e < 8; ++e) {
                        p = fmaf((float)r0[e], q0r[e], p);
                        p = fmaf((float)r1[e], q1r[e], p);
                    }
                }
                p += __shfl_xor(p, 1);            // butterfly: all 8 lanes
                p += __shfl_xor(p, 2);            // end with the full dot
                p += __shfl_xor(p, 4);
                if (gl == 0 && valid) dbuf[ci * slots + sl] = p;
            }
        }
        nsel = W;
    } else {
        // Tie-overflow fallback (~never): exact full scan of this row.
        // Groups stride the refs; butterfly gives every lane the dot; each
        // thread keeps its own top-KK (redundant x8, correct).
        float s[KK];
        #pragma unroll
        for (int j = 0; j < KK; ++j) s[j] = -3.0f;
        for (int g = grp; g < M; g += 32) {
            const unsigned short* rp = &rb[(size_t)g * D_DIM + gl * 8];
            bf16x8 r0 = *(const bf16x8*)rp;
            bf16x8 r1 = *(const bf16x8*)(rp + 64);
            float p = 0.f;
            #pragma unroll
            for (int e = 0; e < 8; ++e) {
                p = fmaf((float)r0[e], q0r[e], p);
                p = fmaf((float)r1[e], q1r[e], p);
            }
            p += __shfl_xor(p, 1);
            p += __shfl_xor(p, 2);
            p += __shfl_xor(p, 4);
            #pragma unroll
            for (int j = 0; j < KK; ++j) {
                float hi = fmaxf(s[j], p), lo = fminf(s[j], p);
                s[j] = hi; p = lo;
            }
        }
        #pragma unroll
        for (int j = 0; j < KK; ++j) dbuf[t * KK + j] = s[j];   // 256*11 = DNF
        nsel = DNF;
    }
    __syncthreads();

    // Final: (kk+1)-th largest over the live dbuf range (wave 0).
    if (t < 64) {
        float s[KK];
        #pragma unroll
        for (int j = 0; j < KK; ++j) s[j] = -3.0f;
        for (int j = t; j < nsel; j += 64) {      // ~5 rounds normal path
            float v = dbuf[j];
            #pragma unroll
            for (int q = 0; q < KK; ++q) {
                float hi = fmaxf(s[q], v), lo = fminf(s[q], v);
                s[q] = hi; v = lo;
            }
        }
        const float cur = kth_largest_64(s, kk, t);
        if (t == 0) out[row] = sqrtf(fmaxf(2.0f - 2.0f * cur, 1e-12f));
    }
}

extern "C" void kernel_launch(void* const* d_in, const int* in_sizes, int n_in,
                              void* d_out, int out_size, void* d_ws, size_t ws_size,
                              hipStream_t stream) {
    const float* z   = (const float*)d_in[0];
    const float* ref = (const float*)d_in[1];
    const int*   kp  = (const int*)d_in[2];
    float* out = (float*)d_out;

    const int N = in_sizes[0] / D_DIM;   // 2048
    const int M = in_sizes[1] / D_DIM;   // 50000

    unsigned short* zbuf = (unsigned short*)d_ws;             // N*128 bf16
    unsigned short* rbuf = zbuf + (size_t)N * D_DIM;          // M*128 bf16
    float* maxes = (float*)(rbuf + (size_t)M * D_DIM);        // N*NSUB f32 (16MB)

    normalize_bf16<<<(N + M + 3) / 4, 256, 0, stream>>>(z, ref, zbuf, rbuf, N, M);

    const int chunk = (M + NCH - 1) / NCH;    // 782
    dim3 grid(N / TQB, NCH);                  // 8 x 64 = 512 blocks

    knn_maxes<<<grid, 512, 0, stream>>>(zbuf, rbuf, maxes, N, M, chunk);
    knn_select<<<N, 256, 0, stream>>>(zbuf, rbuf, maxes, kp, out, M, chunk);
}